// Round 1
// baseline (573.431 us; speedup 1.0000x reference)
//
#include <hip/hip_runtime.h>
#include <math.h>

#define N_NODES 20000
#define E_EDGES 320000
#define E_TOT   (E_EDGES + N_NODES)
#define IN_DIM  384
#define DIM     256
#define LAYERS  3
#define NEG_SLOPE 0.2f
#define LN_EPS 1e-5f

// ---------------- CSR build ----------------
__global__ void count_kernel(const int* __restrict__ ei, int* __restrict__ counts) {
    int e = blockIdx.x * 256 + threadIdx.x;
    if (e >= E_TOT) return;
    int d = (e < E_EDGES) ? ei[E_EDGES + e] : (e - E_EDGES);
    atomicAdd(&counts[d], 1);
}

__global__ __launch_bounds__(1024) void scan_kernel(const int* __restrict__ counts,
                                                    int* __restrict__ row_ptr) {
    __shared__ int sums[1024];
    const int t = threadIdx.x;
    const int CH = (N_NODES + 1023) / 1024;   // 20
    int base = t * CH;
    int local = 0;
    for (int i = 0; i < CH; ++i) {
        int idx = base + i;
        if (idx < N_NODES) local += counts[idx];
    }
    sums[t] = local;
    __syncthreads();
    // Hillis-Steele inclusive scan
    for (int off = 1; off < 1024; off <<= 1) {
        int v = (t >= off) ? sums[t - off] : 0;
        __syncthreads();
        sums[t] += v;
        __syncthreads();
    }
    int run = (t == 0) ? 0 : sums[t - 1];
    for (int i = 0; i < CH; ++i) {
        int idx = base + i;
        if (idx < N_NODES) { row_ptr[idx] = run; run += counts[idx]; }
    }
    if (t == 1023) row_ptr[N_NODES] = sums[1023];
}

__global__ void scatter_kernel(const int* __restrict__ ei, const int* __restrict__ row_ptr,
                               int* __restrict__ cursor, int* __restrict__ csr_src) {
    int e = blockIdx.x * 256 + threadIdx.x;
    if (e >= E_TOT) return;
    int s, d;
    if (e < E_EDGES) { s = ei[e]; d = ei[E_EDGES + e]; }
    else { s = e - E_EDGES; d = s; }
    int pos = row_ptr[d] + atomicAdd(&cursor[d], 1);
    csr_src[pos] = s;
}

// ---------------- f32 tiled GEMM: C = A@B (+bias) ----------------
// A: M x K row-major, B: K x N row-major, C: M x N. N multiple of 64, K multiple of 16.
__global__ __launch_bounds__(256) void gemm_bias(const float* __restrict__ A,
                                                 const float* __restrict__ B,
                                                 const float* __restrict__ bias,
                                                 float* __restrict__ C,
                                                 int M, int K, int N) {
    __shared__ float As[16][64];
    __shared__ float Bs[16][64];
    const int tid = threadIdx.x;
    const int tx = tid & 15, ty = tid >> 4;
    const int bm = blockIdx.y * 64, bn = blockIdx.x * 64;
    float acc[4][4] = {};
    for (int k0 = 0; k0 < K; k0 += 16) {
        {   // A tile 64(m) x 16(k): each thread one float4 along K, store transposed
            int row = tid >> 2, kc = (tid & 3) << 2;
            int gm = bm + row;
            float4 av = make_float4(0.f, 0.f, 0.f, 0.f);
            if (gm < M) av = *reinterpret_cast<const float4*>(A + (size_t)gm * K + (k0 + kc));
            As[kc + 0][row] = av.x;
            As[kc + 1][row] = av.y;
            As[kc + 2][row] = av.z;
            As[kc + 3][row] = av.w;
        }
        {   // B tile 16(k) x 64(n): each thread one float4 along N
            int kr = tid >> 4, nc = (tid & 15) << 2;
            float4 bv = *reinterpret_cast<const float4*>(B + (size_t)(k0 + kr) * N + (bn + nc));
            *reinterpret_cast<float4*>(&Bs[kr][nc]) = bv;
        }
        __syncthreads();
#pragma unroll
        for (int kk = 0; kk < 16; ++kk) {
            float4 a4 = *reinterpret_cast<const float4*>(&As[kk][ty << 2]);
            float4 b4 = *reinterpret_cast<const float4*>(&Bs[kk][tx << 2]);
            float av[4] = {a4.x, a4.y, a4.z, a4.w};
            float bv[4] = {b4.x, b4.y, b4.z, b4.w};
#pragma unroll
            for (int i = 0; i < 4; ++i)
#pragma unroll
                for (int j = 0; j < 4; ++j)
                    acc[i][j] = fmaf(av[i], bv[j], acc[i][j]);
        }
        __syncthreads();
    }
#pragma unroll
    for (int i = 0; i < 4; ++i) {
        int gm = bm + (ty << 2) + i;
        if (gm >= M) continue;
        float4 o = make_float4(acc[i][0], acc[i][1], acc[i][2], acc[i][3]);
        int nc = bn + (tx << 2);
        if (bias) {
            o.x += bias[nc + 0]; o.y += bias[nc + 1];
            o.z += bias[nc + 2]; o.w += bias[nc + 3];
        }
        *reinterpret_cast<float4*>(C + (size_t)gm * N + nc) = o;
    }
}

// ---------------- GATv2 edge aggregation + bias + LayerNorm + residual ----------------
// One wave (64 lanes) per node. lane = h*16 + i; lane owns channels [lane*4, lane*4+4).
__global__ __launch_bounds__(256) void gat_edge(const float* __restrict__ xl,
                                                const float* __restrict__ xr,
                                                const int* __restrict__ row_ptr,
                                                const int* __restrict__ csr_src,
                                                const float* __restrict__ att,
                                                const float* __restrict__ bias,
                                                const float* __restrict__ ln_g,
                                                const float* __restrict__ ln_b,
                                                float* __restrict__ h) {
    const int wave = threadIdx.x >> 6;
    const int lane = threadIdx.x & 63;
    const int node = blockIdx.x * 4 + wave;
    if (node >= N_NODES) return;
    const int c4 = lane << 2;  // channel base = h*64 + i*4 = lane*4

    const float4 xr4 = *reinterpret_cast<const float4*>(xr + (size_t)node * DIM + c4);
    const float4 a4  = *reinterpret_cast<const float4*>(att + c4);

    float m = -INFINITY, s = 0.f;
    float4 acc = make_float4(0.f, 0.f, 0.f, 0.f);

    const int e0 = row_ptr[node], e1 = row_ptr[node + 1];
    for (int e = e0; e < e1; ++e) {
        int src = csr_src[e];
        float4 xj = *reinterpret_cast<const float4*>(xl + (size_t)src * DIM + c4);
        float vx = xj.x + xr4.x; vx = vx > 0.f ? vx : NEG_SLOPE * vx;
        float vy = xj.y + xr4.y; vy = vy > 0.f ? vy : NEG_SLOPE * vy;
        float vz = xj.z + xr4.z; vz = vz > 0.f ? vz : NEG_SLOPE * vz;
        float vw = xj.w + xr4.w; vw = vw > 0.f ? vw : NEG_SLOPE * vw;
        float p = vx * a4.x + vy * a4.y + vz * a4.z + vw * a4.w;
        // reduce over the 16-lane head group
        p += __shfl_xor(p, 1);
        p += __shfl_xor(p, 2);
        p += __shfl_xor(p, 4);
        p += __shfl_xor(p, 8);
        float nm = fmaxf(m, p);
        float scale = __expf(m - nm);   // 0 when m = -inf
        float pe = __expf(p - nm);
        s = s * scale + pe;
        acc.x = acc.x * scale + pe * xj.x;
        acc.y = acc.y * scale + pe * xj.y;
        acc.z = acc.z * scale + pe * xj.z;
        acc.w = acc.w * scale + pe * xj.w;
        m = nm;
    }
    float inv = 1.f / (s + 1e-16f);
    float4 b4 = *reinterpret_cast<const float4*>(bias + c4);
    float ox = acc.x * inv + b4.x;
    float oy = acc.y * inv + b4.y;
    float oz = acc.z * inv + b4.z;
    float ow = acc.w * inv + b4.w;

    // LayerNorm across 256 channels (whole wave)
    float lsum = ox + oy + oz + ow;
    float lsq  = ox * ox + oy * oy + oz * oz + ow * ow;
#pragma unroll
    for (int off = 1; off < 64; off <<= 1) {
        lsum += __shfl_xor(lsum, off);
        lsq  += __shfl_xor(lsq, off);
    }
    float mu = lsum * (1.f / 256.f);
    float var = lsq * (1.f / 256.f) - mu * mu;
    float rstd = rsqrtf(var + LN_EPS);
    float4 g4 = *reinterpret_cast<const float4*>(ln_g + c4);
    float4 lb4 = *reinterpret_cast<const float4*>(ln_b + c4);
    float4 hv = *reinterpret_cast<const float4*>(h + (size_t)node * DIM + c4);
    hv.x += (ox - mu) * rstd * g4.x + lb4.x;
    hv.y += (oy - mu) * rstd * g4.y + lb4.y;
    hv.z += (oz - mu) * rstd * g4.z + lb4.z;
    hv.w += (ow - mu) * rstd * g4.w + lb4.w;
    *reinterpret_cast<float4*>(h + (size_t)node * DIM + c4) = hv;
}

// ---------------- final L2 row-normalize ----------------
__global__ __launch_bounds__(256) void normalize_kernel(const float* __restrict__ h,
                                                        float* __restrict__ out) {
    const int wave = threadIdx.x >> 6;
    const int lane = threadIdx.x & 63;
    const int node = blockIdx.x * 4 + wave;
    if (node >= N_NODES) return;
    float4 v = *reinterpret_cast<const float4*>(h + (size_t)node * DIM + (lane << 2));
    float sq = v.x * v.x + v.y * v.y + v.z * v.z + v.w * v.w;
#pragma unroll
    for (int off = 1; off < 64; off <<= 1) sq += __shfl_xor(sq, off);
    float inv = 1.f / fmaxf(sqrtf(sq), 1e-12f);
    float4 o = make_float4(v.x * inv, v.y * inv, v.z * inv, v.w * inv);
    *reinterpret_cast<float4*>(out + (size_t)node * DIM + (lane << 2)) = o;
}

extern "C" void kernel_launch(void* const* d_in, const int* in_sizes, int n_in,
                              void* d_out, int out_size, void* d_ws, size_t ws_size,
                              hipStream_t stream) {
    const float* x    = (const float*)d_in[0];
    const int*   ei   = (const int*)d_in[1];
    const float* w_in = (const float*)d_in[2];
    const float* b_in = (const float*)d_in[3];
    const float* wl   = (const float*)d_in[4];
    const float* wr   = (const float*)d_in[5];
    const float* att  = (const float*)d_in[6];
    const float* bias = (const float*)d_in[7];
    const float* ln_g = (const float*)d_in[8];
    const float* ln_b = (const float*)d_in[9];

    float* h  = (float*)d_ws;                       // N*DIM
    float* xl = h + (size_t)N_NODES * DIM;          // N*DIM
    float* xr = xl + (size_t)N_NODES * DIM;         // N*DIM
    int* row_ptr = (int*)(xr + (size_t)N_NODES * DIM);  // N+1
    int* counts  = row_ptr + (N_NODES + 1);         // N
    int* cursor  = counts + N_NODES;                // N
    int* csr_src = cursor + N_NODES;                // E_TOT

    // counts + cursor are contiguous: zero both in one memset
    hipMemsetAsync(counts, 0, sizeof(int) * 2 * N_NODES, stream);
    count_kernel<<<(E_TOT + 255) / 256, 256, 0, stream>>>(ei, counts);
    scan_kernel<<<1, 1024, 0, stream>>>(counts, row_ptr);
    scatter_kernel<<<(E_TOT + 255) / 256, 256, 0, stream>>>(ei, row_ptr, cursor, csr_src);

    dim3 gemm_grid(DIM / 64, (N_NODES + 63) / 64);
    gemm_bias<<<gemm_grid, 256, 0, stream>>>(x, w_in, b_in, h, N_NODES, IN_DIM, DIM);

    for (int l = 0; l < LAYERS; ++l) {
        const float* wl_l = wl + (size_t)l * DIM * DIM;
        const float* wr_l = wr + (size_t)l * DIM * DIM;
        gemm_bias<<<gemm_grid, 256, 0, stream>>>(h, wl_l, nullptr, xl, N_NODES, DIM, DIM);
        gemm_bias<<<gemm_grid, 256, 0, stream>>>(h, wr_l, nullptr, xr, N_NODES, DIM, DIM);
        gat_edge<<<(N_NODES + 3) / 4, 256, 0, stream>>>(
            xl, xr, row_ptr, csr_src,
            att + (size_t)l * DIM, bias + (size_t)l * DIM,
            ln_g + (size_t)l * DIM, ln_b + (size_t)l * DIM, h);
    }

    normalize_kernel<<<(N_NODES + 3) / 4, 256, 0, stream>>>(h, (float*)d_out);
}

// Round 2
// 394.034 us; speedup vs baseline: 1.4553x; 1.4553x over previous
//
#include <hip/hip_runtime.h>
#include <math.h>

#define N_NODES 20000
#define E_EDGES 320000
#define E_TOT   (E_EDGES + N_NODES)
#define IN_DIM  384
#define DIM     256
#define LAYERS  3
#define NEG_SLOPE 0.2f
#define LN_EPS 1e-5f

typedef unsigned short u16;
typedef unsigned int u32;
typedef __attribute__((ext_vector_type(8))) short short8;
typedef __attribute__((ext_vector_type(8))) __bf16 bf16x8;
typedef __attribute__((ext_vector_type(4))) float f32x4;

// ---- bf16 split helpers (RNE) ----
__device__ inline u16 f2bf(float f) {
    u32 u = __builtin_bit_cast(u32, f);
    return (u16)((u + 0x7fffu + ((u >> 16) & 1u)) >> 16);
}
__device__ inline float bf2f(u16 s) {
    u32 u = (u32)s << 16;
    return __builtin_bit_cast(float, u);
}

__device__ inline f32x4 mfma_bf16(short8 a, short8 b, f32x4 c) {
    return __builtin_amdgcn_mfma_f32_16x16x32_bf16(
        __builtin_bit_cast(bf16x8, a), __builtin_bit_cast(bf16x8, b), c, 0, 0, 0);
}

__device__ inline void gl_lds16(const u16* g, u16* l) {
    __builtin_amdgcn_global_load_lds(
        (const __attribute__((address_space(1))) u32*)g,
        (__attribute__((address_space(3))) u32*)l, 16, 0, 0);
}

// ---------------- CSR build ----------------
__global__ void count_kernel(const int* __restrict__ ei, int* __restrict__ counts) {
    int e = blockIdx.x * 256 + threadIdx.x;
    if (e >= E_TOT) return;
    int d = (e < E_EDGES) ? ei[E_EDGES + e] : (e - E_EDGES);
    atomicAdd(&counts[d], 1);
}

__global__ __launch_bounds__(1024) void scan_kernel(const int* __restrict__ counts,
                                                    int* __restrict__ row_ptr) {
    __shared__ int sums[1024];
    const int t = threadIdx.x;
    const int CH = (N_NODES + 1023) / 1024;
    int base = t * CH;
    int local = 0;
    for (int i = 0; i < CH; ++i) {
        int idx = base + i;
        if (idx < N_NODES) local += counts[idx];
    }
    sums[t] = local;
    __syncthreads();
    for (int off = 1; off < 1024; off <<= 1) {
        int v = (t >= off) ? sums[t - off] : 0;
        __syncthreads();
        sums[t] += v;
        __syncthreads();
    }
    int run = (t == 0) ? 0 : sums[t - 1];
    for (int i = 0; i < CH; ++i) {
        int idx = base + i;
        if (idx < N_NODES) { row_ptr[idx] = run; run += counts[idx]; }
    }
    if (t == 1023) row_ptr[N_NODES] = sums[1023];
}

__global__ void scatter_kernel(const int* __restrict__ ei, const int* __restrict__ row_ptr,
                               int* __restrict__ cursor, int* __restrict__ csr_src) {
    int e = blockIdx.x * 256 + threadIdx.x;
    if (e >= E_TOT) return;
    int s, d;
    if (e < E_EDGES) { s = ei[e]; d = ei[E_EDGES + e]; }
    else { s = e - E_EDGES; d = s; }
    int pos = row_ptr[d] + atomicAdd(&cursor[d], 1);
    csr_src[pos] = s;
}

// ---------------- conversion kernels ----------------
// elementwise f32 -> (hi, lo) bf16 split, 4 elems/thread
__global__ void convert_split(const float* __restrict__ in, u16* __restrict__ hi,
                              u16* __restrict__ lo, int n4) {
    int i = blockIdx.x * 256 + threadIdx.x;
    if (i >= n4) return;
    float4 v = reinterpret_cast<const float4*>(in)[i];
    float a[4] = {v.x, v.y, v.z, v.w};
    u16 h[4], l[4];
#pragma unroll
    for (int j = 0; j < 4; ++j) {
        h[j] = f2bf(a[j]);
        l[j] = f2bf(a[j] - bf2f(h[j]));
    }
    reinterpret_cast<ushort4*>(hi)[i] = make_ushort4(h[0], h[1], h[2], h[3]);
    reinterpret_cast<ushort4*>(lo)[i] = make_ushort4(l[0], l[1], l[2], l[3]);
}

// weights: w_in [384][256] -> [256][384] (transposed); wl/wr [3][256][256] ->
// per-layer [512][256] with rows 0-255 = Wl^T, 256-511 = Wr^T. One flat index space.
#define W_IN_ELEMS (IN_DIM * DIM)          // 98304 (output [256][384])
#define W_LR_ELEMS (2 * DIM * DIM)         // 131072 per layer ([512][256])
#define W_TOT (W_IN_ELEMS + LAYERS * W_LR_ELEMS)
__global__ void convert_weights(const float* __restrict__ w_in, const float* __restrict__ wl,
                                const float* __restrict__ wr, u16* __restrict__ hi,
                                u16* __restrict__ lo) {
    int idx = blockIdx.x * 256 + threadIdx.x;
    if (idx >= W_TOT) return;
    float v;
    if (idx < W_IN_ELEMS) {
        int n = idx / IN_DIM, k = idx % IN_DIM;
        v = w_in[k * DIM + n];
    } else {
        int j = idx - W_IN_ELEMS;
        int l = j / W_LR_ELEMS;
        int r = j % W_LR_ELEMS;
        int n = r >> 8, k = r & 255;
        const float* W = (n < DIM) ? wl : wr;
        v = W[l * DIM * DIM + k * DIM + (n & 255)];
    }
    u16 h = f2bf(v);
    hi[idx] = h;
    lo[idx] = f2bf(v - bf2f(h));
}

// ---------------- split-bf16 MFMA GEMM ----------------
// C[M][ldc] = Ah+Al (M x K, row-major bf16 split) @ (Bh+Bl)^T where B is given
// as B^T: [ldc][K] row-major. 128x128 tile, BK=32, 4 waves (2x2), 3-product split.
#define BM 128
#define BN 128
#define BK 32
template <int K, bool BIAS, bool HILO>
__global__ __launch_bounds__(256) void gemm_mfma(
    const u16* __restrict__ Ah, const u16* __restrict__ Al,
    const u16* __restrict__ Bh, const u16* __restrict__ Bl,
    const float* __restrict__ bias,
    float* __restrict__ C, u16* __restrict__ Chi, u16* __restrict__ Clo,
    int M, int ldc) {
    __shared__ u16 lAh[BM * BK], lAl[BM * BK], lBh[BN * BK], lBl[BN * BK];
    const int tid = threadIdx.x;
    const int w = tid >> 6, lane = tid & 63;
    const int wm = w >> 1, wn = w & 1;
    const int bm = blockIdx.y * BM, bn = blockIdx.x * BN;

    f32x4 acc[4][4] = {};

    const int sc = (lane & 3) * 8;          // ushort offset within a 32-elem row
    const int srsub = lane >> 2;            // 0..15 row within wave chunk
    const int fr = lane & 15, fk = (lane >> 4) * 8;

    for (int k0 = 0; k0 < K; k0 += BK) {
#pragma unroll
        for (int i = 0; i < 2; ++i) {
            int r = i * 64 + w * 16 + srsub;
            int lo_off = i * 2048 + w * 512;     // ushort units (4KB/2, 1KB/2)
            int ra = min(bm + r, M - 1);
            gl_lds16(Ah + (size_t)ra * K + k0 + sc, &lAh[lo_off]);
            gl_lds16(Al + (size_t)ra * K + k0 + sc, &lAl[lo_off]);
            int rb = bn + r;
            gl_lds16(Bh + (size_t)rb * K + k0 + sc, &lBh[lo_off]);
            gl_lds16(Bl + (size_t)rb * K + k0 + sc, &lBl[lo_off]);
        }
        __syncthreads();

        short8 a_h[4], a_l[4], b_h[4], b_l[4];
#pragma unroll
        for (int mi = 0; mi < 4; ++mi) {
            int rowi = wm * 64 + mi * 16 + fr;
            a_h[mi] = *reinterpret_cast<const short8*>(&lAh[rowi * BK + fk]);
            a_l[mi] = *reinterpret_cast<const short8*>(&lAl[rowi * BK + fk]);
        }
#pragma unroll
        for (int ni = 0; ni < 4; ++ni) {
            int rowi = wn * 64 + ni * 16 + fr;
            b_h[ni] = *reinterpret_cast<const short8*>(&lBh[rowi * BK + fk]);
            b_l[ni] = *reinterpret_cast<const short8*>(&lBl[rowi * BK + fk]);
        }
#pragma unroll
        for (int mi = 0; mi < 4; ++mi)
#pragma unroll
            for (int ni = 0; ni < 4; ++ni) {
                acc[mi][ni] = mfma_bf16(a_h[mi], b_h[ni], acc[mi][ni]);
                acc[mi][ni] = mfma_bf16(a_h[mi], b_l[ni], acc[mi][ni]);
                acc[mi][ni] = mfma_bf16(a_l[mi], b_h[ni], acc[mi][ni]);
            }
        __syncthreads();
    }

    // epilogue: C/D layout col = lane&15, row = (lane>>4)*4 + reg
    const int fq = lane >> 4;
#pragma unroll
    for (int mi = 0; mi < 4; ++mi) {
#pragma unroll
        for (int r = 0; r < 4; ++r) {
            int row = bm + wm * 64 + mi * 16 + fq * 4 + r;
            if (row >= M) continue;
#pragma unroll
            for (int ni = 0; ni < 4; ++ni) {
                int col = bn + wn * 64 + ni * 16 + fr;
                float v = acc[mi][ni][r];
                if (BIAS) v += bias[col];
                C[(size_t)row * ldc + col] = v;
                if (HILO) {
                    u16 hb = f2bf(v);
                    Chi[(size_t)row * ldc + col] = hb;
                    Clo[(size_t)row * ldc + col] = f2bf(v - bf2f(hb));
                }
            }
        }
    }
}

// ---------------- GATv2 edge aggregation + bias + LN + residual + split-out ----------------
// xlr: [N][512] f32, cols 0-255 = xl, 256-511 = xr. One wave per node.
__global__ __launch_bounds__(256) void gat_edge(const float* __restrict__ xlr,
                                                const int* __restrict__ row_ptr,
                                                const int* __restrict__ csr_src,
                                                const float* __restrict__ att,
                                                const float* __restrict__ bias,
                                                const float* __restrict__ ln_g,
                                                const float* __restrict__ ln_b,
                                                float* __restrict__ h,
                                                u16* __restrict__ h_hi,
                                                u16* __restrict__ h_lo) {
    const int wave = threadIdx.x >> 6;
    const int lane = threadIdx.x & 63;
    const int node = blockIdx.x * 4 + wave;
    if (node >= N_NODES) return;
    const int c4 = lane << 2;

    const float4 xr4 = *reinterpret_cast<const float4*>(xlr + (size_t)node * 512 + 256 + c4);
    const float4 a4  = *reinterpret_cast<const float4*>(att + c4);

    float m = -INFINITY, s = 0.f;
    float4 acc = make_float4(0.f, 0.f, 0.f, 0.f);

    const int e0 = row_ptr[node], e1 = row_ptr[node + 1];
    for (int e = e0; e < e1; ++e) {
        int src = csr_src[e];
        float4 xj = *reinterpret_cast<const float4*>(xlr + (size_t)src * 512 + c4);
        float vx = xj.x + xr4.x; vx = vx > 0.f ? vx : NEG_SLOPE * vx;
        float vy = xj.y + xr4.y; vy = vy > 0.f ? vy : NEG_SLOPE * vy;
        float vz = xj.z + xr4.z; vz = vz > 0.f ? vz : NEG_SLOPE * vz;
        float vw = xj.w + xr4.w; vw = vw > 0.f ? vw : NEG_SLOPE * vw;
        float p = vx * a4.x + vy * a4.y + vz * a4.z + vw * a4.w;
        p += __shfl_xor(p, 1);
        p += __shfl_xor(p, 2);
        p += __shfl_xor(p, 4);
        p += __shfl_xor(p, 8);
        float nm = fmaxf(m, p);
        float scale = __expf(m - nm);
        float pe = __expf(p - nm);
        s = s * scale + pe;
        acc.x = acc.x * scale + pe * xj.x;
        acc.y = acc.y * scale + pe * xj.y;
        acc.z = acc.z * scale + pe * xj.z;
        acc.w = acc.w * scale + pe * xj.w;
        m = nm;
    }
    float inv = 1.f / (s + 1e-16f);
    float4 b4 = *reinterpret_cast<const float4*>(bias + c4);
    float ox = acc.x * inv + b4.x;
    float oy = acc.y * inv + b4.y;
    float oz = acc.z * inv + b4.z;
    float ow = acc.w * inv + b4.w;

    float lsum = ox + oy + oz + ow;
    float lsq  = ox * ox + oy * oy + oz * oz + ow * ow;
#pragma unroll
    for (int off = 1; off < 64; off <<= 1) {
        lsum += __shfl_xor(lsum, off);
        lsq  += __shfl_xor(lsq, off);
    }
    float mu = lsum * (1.f / 256.f);
    float var = lsq * (1.f / 256.f) - mu * mu;
    float rstd = rsqrtf(var + LN_EPS);
    float4 g4  = *reinterpret_cast<const float4*>(ln_g + c4);
    float4 lb4 = *reinterpret_cast<const float4*>(ln_b + c4);
    float4 hv  = *reinterpret_cast<const float4*>(h + (size_t)node * DIM + c4);
    hv.x += (ox - mu) * rstd * g4.x + lb4.x;
    hv.y += (oy - mu) * rstd * g4.y + lb4.y;
    hv.z += (oz - mu) * rstd * g4.z + lb4.z;
    hv.w += (ow - mu) * rstd * g4.w + lb4.w;
    *reinterpret_cast<float4*>(h + (size_t)node * DIM + c4) = hv;

    float vals[4] = {hv.x, hv.y, hv.z, hv.w};
    u16 hh[4], hl[4];
#pragma unroll
    for (int j = 0; j < 4; ++j) {
        hh[j] = f2bf(vals[j]);
        hl[j] = f2bf(vals[j] - bf2f(hh[j]));
    }
    *reinterpret_cast<ushort4*>(h_hi + (size_t)node * DIM + c4) = make_ushort4(hh[0], hh[1], hh[2], hh[3]);
    *reinterpret_cast<ushort4*>(h_lo + (size_t)node * DIM + c4) = make_ushort4(hl[0], hl[1], hl[2], hl[3]);
}

// ---------------- final L2 row-normalize ----------------
__global__ __launch_bounds__(256) void normalize_kernel(const float* __restrict__ h,
                                                        float* __restrict__ out) {
    const int wave = threadIdx.x >> 6;
    const int lane = threadIdx.x & 63;
    const int node = blockIdx.x * 4 + wave;
    if (node >= N_NODES) return;
    float4 v = *reinterpret_cast<const float4*>(h + (size_t)node * DIM + (lane << 2));
    float sq = v.x * v.x + v.y * v.y + v.z * v.z + v.w * v.w;
#pragma unroll
    for (int off = 1; off < 64; off <<= 1) sq += __shfl_xor(sq, off);
    float inv = 1.f / fmaxf(sqrtf(sq), 1e-12f);
    float4 o = make_float4(v.x * inv, v.y * inv, v.z * inv, v.w * inv);
    *reinterpret_cast<float4*>(out + (size_t)node * DIM + (lane << 2)) = o;
}

extern "C" void kernel_launch(void* const* d_in, const int* in_sizes, int n_in,
                              void* d_out, int out_size, void* d_ws, size_t ws_size,
                              hipStream_t stream) {
    const float* x    = (const float*)d_in[0];
    const int*   ei   = (const int*)d_in[1];
    const float* w_in = (const float*)d_in[2];
    const float* b_in = (const float*)d_in[3];
    const float* wl   = (const float*)d_in[4];
    const float* wr   = (const float*)d_in[5];
    const float* att  = (const float*)d_in[6];
    const float* bias = (const float*)d_in[7];
    const float* ln_g = (const float*)d_in[8];
    const float* ln_b = (const float*)d_in[9];

    char* p = (char*)d_ws;
    float* h    = (float*)p;              p += (size_t)N_NODES * DIM * 4;    // 20.48 MB
    u16*   h_hi = (u16*)p;                p += (size_t)N_NODES * DIM * 2;    // 10.24 MB
    u16*   h_lo = (u16*)p;                p += (size_t)N_NODES * DIM * 2;    // 10.24 MB
    float* xlr  = (float*)p;              p += (size_t)N_NODES * 512 * 4;    // 40.96 MB
    u16*   conv_hi = (u16*)p;             p += (size_t)W_TOT * 2;
    u16*   conv_lo = (u16*)p;             p += (size_t)W_TOT * 2;
    int* row_ptr = (int*)p;               p += (N_NODES + 1) * 4;
    int* counts  = (int*)p;               p += N_NODES * 4;
    int* cursor  = (int*)p;               p += N_NODES * 4;
    int* csr_src = (int*)p;

    // x_hi/x_lo alias the xlr region (x split only needed before layer GEMMs run)
    u16* x_hi = (u16*)xlr;
    u16* x_lo = x_hi + (size_t)N_NODES * IN_DIM;

    hipMemsetAsync(counts, 0, sizeof(int) * 2 * N_NODES, stream);
    count_kernel<<<(E_TOT + 255) / 256, 256, 0, stream>>>(ei, counts);
    scan_kernel<<<1, 1024, 0, stream>>>(counts, row_ptr);
    scatter_kernel<<<(E_TOT + 255) / 256, 256, 0, stream>>>(ei, row_ptr, cursor, csr_src);

    {   // split x and weights
        int n4 = N_NODES * IN_DIM / 4;
        convert_split<<<(n4 + 255) / 256, 256, 0, stream>>>(x, x_hi, x_lo, n4);
        convert_weights<<<(W_TOT + 255) / 256, 256, 0, stream>>>(w_in, wl, wr, conv_hi, conv_lo);
    }

    const u16* wt_hi = conv_hi;                       // [256][384]
    const u16* wt_lo = conv_lo;

    // input projection: h = x @ w_in + b_in, plus bf16 split of h
    gemm_mfma<IN_DIM, true, true><<<dim3(DIM / BN, (N_NODES + BM - 1) / BM), 256, 0, stream>>>(
        x_hi, x_lo, wt_hi, wt_lo, b_in, h, h_hi, h_lo, N_NODES, DIM);

    for (int l = 0; l < LAYERS; ++l) {
        const u16* wlr_hi = conv_hi + W_IN_ELEMS + (size_t)l * W_LR_ELEMS;  // [512][256]
        const u16* wlr_lo = conv_lo + W_IN_ELEMS + (size_t)l * W_LR_ELEMS;
        gemm_mfma<DIM, false, false><<<dim3(512 / BN, (N_NODES + BM - 1) / BM), 256, 0, stream>>>(
            h_hi, h_lo, wlr_hi, wlr_lo, nullptr, xlr, nullptr, nullptr, N_NODES, 512);
        gat_edge<<<(N_NODES + 3) / 4, 256, 0, stream>>>(
            xlr, row_ptr, csr_src,
            att + (size_t)l * DIM, bias + (size_t)l * DIM,
            ln_g + (size_t)l * DIM, ln_b + (size_t)l * DIM, h, h_hi, h_lo);
    }

    normalize_kernel<<<(N_NODES + 3) / 4, 256, 0, stream>>>(h, (float*)d_out);
}

// Round 3
// 273.298 us; speedup vs baseline: 2.0982x; 1.4418x over previous
//
#include <hip/hip_runtime.h>
#include <math.h>

#define N_NODES 20000
#define E_EDGES 320000
#define E_TOT   (E_EDGES + N_NODES)
#define IN_DIM  384
#define DIM     256
#define LAYERS  3
#define NEG_SLOPE 0.2f
#define LN_EPS 1e-5f

typedef unsigned short u16;
typedef unsigned int u32;
typedef __attribute__((ext_vector_type(8))) short short8;
typedef __attribute__((ext_vector_type(8))) __bf16 bf16x8;
typedef __attribute__((ext_vector_type(4))) float f32x4;

__device__ inline u16 f2bf(float f) {
    u32 u = __builtin_bit_cast(u32, f);
    return (u16)((u + 0x7fffu + ((u >> 16) & 1u)) >> 16);
}
__device__ inline float bf2f(u16 s) {
    u32 u = (u32)s << 16;
    return __builtin_bit_cast(float, u);
}
__device__ inline float4 cvt4(ushort4 u) {
    return make_float4(bf2f(u.x), bf2f(u.y), bf2f(u.z), bf2f(u.w));
}

__device__ inline f32x4 mfma_bf16(short8 a, short8 b, f32x4 c) {
    return __builtin_amdgcn_mfma_f32_16x16x32_bf16(
        __builtin_bit_cast(bf16x8, a), __builtin_bit_cast(bf16x8, b), c, 0, 0, 0);
}

__device__ inline void gl_lds16(const u16* g, u16* l) {
    __builtin_amdgcn_global_load_lds(
        (const __attribute__((address_space(1))) u32*)g,
        (__attribute__((address_space(3))) u32*)l, 16, 0, 0);
}

// ---------------- CSR build ----------------
__global__ void count_kernel(const int* __restrict__ ei, int* __restrict__ counts) {
    int e = blockIdx.x * 256 + threadIdx.x;
    if (e >= E_TOT) return;
    int d = (e < E_EDGES) ? ei[E_EDGES + e] : (e - E_EDGES);
    atomicAdd(&counts[d], 1);
}

__global__ __launch_bounds__(1024) void scan_kernel(const int* __restrict__ counts,
                                                    int* __restrict__ row_ptr) {
    __shared__ int sums[1024];
    const int t = threadIdx.x;
    const int CH = (N_NODES + 1023) / 1024;
    int base = t * CH;
    int local = 0;
    for (int i = 0; i < CH; ++i) {
        int idx = base + i;
        if (idx < N_NODES) local += counts[idx];
    }
    sums[t] = local;
    __syncthreads();
    for (int off = 1; off < 1024; off <<= 1) {
        int v = (t >= off) ? sums[t - off] : 0;
        __syncthreads();
        sums[t] += v;
        __syncthreads();
    }
    int run = (t == 0) ? 0 : sums[t - 1];
    for (int i = 0; i < CH; ++i) {
        int idx = base + i;
        if (idx < N_NODES) { row_ptr[idx] = run; run += counts[idx]; }
    }
    if (t == 1023) row_ptr[N_NODES] = sums[1023];
}

__global__ void scatter_kernel(const int* __restrict__ ei, const int* __restrict__ row_ptr,
                               int* __restrict__ cursor, int* __restrict__ csr_src) {
    int e = blockIdx.x * 256 + threadIdx.x;
    if (e >= E_TOT) return;
    int s, d;
    if (e < E_EDGES) { s = ei[e]; d = ei[E_EDGES + e]; }
    else { s = e - E_EDGES; d = s; }
    int pos = row_ptr[d] + atomicAdd(&cursor[d], 1);
    csr_src[pos] = s;
}

// ---------------- conversion kernels ----------------
__global__ void convert_bf16(const float* __restrict__ in, u16* __restrict__ out, int n4) {
    int i = blockIdx.x * 256 + threadIdx.x;
    if (i >= n4) return;
    float4 v = reinterpret_cast<const float4*>(in)[i];
    reinterpret_cast<ushort4*>(out)[i] =
        make_ushort4(f2bf(v.x), f2bf(v.y), f2bf(v.z), f2bf(v.w));
}

// weights: w_in [384][256] -> [256][384] (transposed); wl/wr [3][256][256] ->
// per-layer [512][256] with rows 0-255 = Wl^T, 256-511 = Wr^T.
#define W_IN_ELEMS (IN_DIM * DIM)
#define W_LR_ELEMS (2 * DIM * DIM)
#define W_TOT (W_IN_ELEMS + LAYERS * W_LR_ELEMS)
__global__ void convert_weights(const float* __restrict__ w_in, const float* __restrict__ wl,
                                const float* __restrict__ wr, u16* __restrict__ out) {
    int idx = blockIdx.x * 256 + threadIdx.x;
    if (idx >= W_TOT) return;
    float v;
    if (idx < W_IN_ELEMS) {
        int n = idx / IN_DIM, k = idx % IN_DIM;
        v = w_in[k * DIM + n];
    } else {
        int j = idx - W_IN_ELEMS;
        int l = j / W_LR_ELEMS;
        int r = j % W_LR_ELEMS;
        int n = r >> 8, k = r & 255;
        const float* W = (n < DIM) ? wl : wr;
        v = W[l * DIM * DIM + k * DIM + (n & 255)];
    }
    out[idx] = f2bf(v);
}

// ---------------- bf16 MFMA GEMM ----------------
// C = A (M x K bf16 row-major) @ B^T (B given as [ldc][K] bf16 row-major).
// 128x128 tile, BK=32, 4 waves (2x2). LDS 16B-block XOR swizzle:
// LDS[row][blk b] = G[row][b ^ ((row>>1)&3)]  (rows are 4 x 16B blocks).
#define BM 128
#define BN 128
#define BK 32
// MODE 0: +bias, write C f32 and Cbf bf16. MODE 1: write Cbf bf16 only.
template <int K, int MODE>
__global__ __launch_bounds__(256) void gemm_mfma(
    const u16* __restrict__ A, const u16* __restrict__ B,
    const float* __restrict__ bias,
    float* __restrict__ C, u16* __restrict__ Cbf,
    int M, int ldc) {
    __shared__ u16 lA[BM * BK], lB[BN * BK];
    const int tid = threadIdx.x;
    const int w = tid >> 6, lane = tid & 63;
    const int wm = w >> 1, wn = w & 1;
    const int bm = blockIdx.y * BM, bn = blockIdx.x * BN;

    f32x4 acc[4][4] = {};

    const int srsub = lane >> 2;                       // 0..15 row within 16-row group
    const int cbs = (((lane & 3) ^ ((srsub >> 1) & 3)) << 3);  // swizzled src col (ushorts)
    const int fr = lane & 15, q = lane >> 4;
    const int fks = ((q ^ ((fr >> 1) & 3)) << 3);      // swizzled read col (ushorts)

    for (int k0 = 0; k0 < K; k0 += BK) {
#pragma unroll
        for (int i = 0; i < 2; ++i) {
            int r = i * 64 + w * 16 + srsub;
            int off = i * 2048 + w * 512;              // ushort units
            int ra = min(bm + r, M - 1);
            gl_lds16(A + (size_t)ra * K + k0 + cbs, &lA[off]);
            int rb = bn + r;
            gl_lds16(B + (size_t)rb * K + k0 + cbs, &lB[off]);
        }
        __syncthreads();

        short8 a_f[4], b_f[4];
#pragma unroll
        for (int mi = 0; mi < 4; ++mi)
            a_f[mi] = *reinterpret_cast<const short8*>(&lA[(wm * 64 + mi * 16 + fr) * BK + fks]);
#pragma unroll
        for (int ni = 0; ni < 4; ++ni)
            b_f[ni] = *reinterpret_cast<const short8*>(&lB[(wn * 64 + ni * 16 + fr) * BK + fks]);
#pragma unroll
        for (int mi = 0; mi < 4; ++mi)
#pragma unroll
            for (int ni = 0; ni < 4; ++ni)
                acc[mi][ni] = mfma_bf16(a_f[mi], b_f[ni], acc[mi][ni]);
        __syncthreads();
    }

    // epilogue: C/D layout col = lane&15, row = (lane>>4)*4 + reg
#pragma unroll
    for (int mi = 0; mi < 4; ++mi) {
#pragma unroll
        for (int r = 0; r < 4; ++r) {
            int row = bm + wm * 64 + mi * 16 + q * 4 + r;
            if (row >= M) continue;
#pragma unroll
            for (int ni = 0; ni < 4; ++ni) {
                int col = bn + wn * 64 + ni * 16 + fr;
                float v = acc[mi][ni][r];
                if (MODE == 0) {
                    v += bias[col];
                    C[(size_t)row * ldc + col] = v;
                }
                Cbf[(size_t)row * ldc + col] = f2bf(v);
            }
        }
    }
}

// ---------------- GATv2 edge aggregation + bias + LN + residual ----------------
// xlr_bf: [N][512] bf16, cols 0-255 = xl, 256-511 = xr. One wave per node.
// 2-edge unrolled independent online-softmax states, merged at the end.
__global__ __launch_bounds__(256) void gat_edge(const u16* __restrict__ xlr_bf,
                                                const int* __restrict__ row_ptr,
                                                const int* __restrict__ csr_src,
                                                const float* __restrict__ att,
                                                const float* __restrict__ bias,
                                                const float* __restrict__ ln_g,
                                                const float* __restrict__ ln_b,
                                                float* __restrict__ h,
                                                u16* __restrict__ h_bf) {
    const int wave = threadIdx.x >> 6;
    const int lane = threadIdx.x & 63;
    const int node = blockIdx.x * 4 + wave;
    if (node >= N_NODES) return;
    const int c4 = lane << 2;

    const float4 xr4 = cvt4(*reinterpret_cast<const ushort4*>(xlr_bf + (size_t)node * 512 + 256 + c4));
    const float4 a4  = *reinterpret_cast<const float4*>(att + c4);

    float mA = -INFINITY, sA = 0.f;
    float mB = -INFINITY, sB = 0.f;
    float4 accA = make_float4(0.f, 0.f, 0.f, 0.f);
    float4 accB = make_float4(0.f, 0.f, 0.f, 0.f);

    const int e0 = row_ptr[node], e1 = row_ptr[node + 1];
    int e = e0;
    for (; e + 1 < e1; e += 2) {
        int srcA = csr_src[e], srcB = csr_src[e + 1];
        ushort4 ua = *reinterpret_cast<const ushort4*>(xlr_bf + (size_t)srcA * 512 + c4);
        ushort4 ub = *reinterpret_cast<const ushort4*>(xlr_bf + (size_t)srcB * 512 + c4);
        float4 xa = cvt4(ua), xb = cvt4(ub);

        float vax = xa.x + xr4.x; vax = vax > 0.f ? vax : NEG_SLOPE * vax;
        float vay = xa.y + xr4.y; vay = vay > 0.f ? vay : NEG_SLOPE * vay;
        float vaz = xa.z + xr4.z; vaz = vaz > 0.f ? vaz : NEG_SLOPE * vaz;
        float vaw = xa.w + xr4.w; vaw = vaw > 0.f ? vaw : NEG_SLOPE * vaw;
        float pA = vax * a4.x + vay * a4.y + vaz * a4.z + vaw * a4.w;

        float vbx = xb.x + xr4.x; vbx = vbx > 0.f ? vbx : NEG_SLOPE * vbx;
        float vby = xb.y + xr4.y; vby = vby > 0.f ? vby : NEG_SLOPE * vby;
        float vbz = xb.z + xr4.z; vbz = vbz > 0.f ? vbz : NEG_SLOPE * vbz;
        float vbw = xb.w + xr4.w; vbw = vbw > 0.f ? vbw : NEG_SLOPE * vbw;
        float pB = vbx * a4.x + vby * a4.y + vbz * a4.z + vbw * a4.w;

        pA += __shfl_xor(pA, 1); pB += __shfl_xor(pB, 1);
        pA += __shfl_xor(pA, 2); pB += __shfl_xor(pB, 2);
        pA += __shfl_xor(pA, 4); pB += __shfl_xor(pB, 4);
        pA += __shfl_xor(pA, 8); pB += __shfl_xor(pB, 8);

        float nmA = fmaxf(mA, pA);
        float scA = __expf(mA - nmA), peA = __expf(pA - nmA);
        sA = sA * scA + peA;
        accA.x = accA.x * scA + peA * xa.x;
        accA.y = accA.y * scA + peA * xa.y;
        accA.z = accA.z * scA + peA * xa.z;
        accA.w = accA.w * scA + peA * xa.w;
        mA = nmA;

        float nmB = fmaxf(mB, pB);
        float scB = __expf(mB - nmB), peB = __expf(pB - nmB);
        sB = sB * scB + peB;
        accB.x = accB.x * scB + peB * xb.x;
        accB.y = accB.y * scB + peB * xb.y;
        accB.z = accB.z * scB + peB * xb.z;
        accB.w = accB.w * scB + peB * xb.w;
        mB = nmB;
    }
    if (e < e1) {
        int src = csr_src[e];
        ushort4 ua = *reinterpret_cast<const ushort4*>(xlr_bf + (size_t)src * 512 + c4);
        float4 xa = cvt4(ua);
        float vax = xa.x + xr4.x; vax = vax > 0.f ? vax : NEG_SLOPE * vax;
        float vay = xa.y + xr4.y; vay = vay > 0.f ? vay : NEG_SLOPE * vay;
        float vaz = xa.z + xr4.z; vaz = vaz > 0.f ? vaz : NEG_SLOPE * vaz;
        float vaw = xa.w + xr4.w; vaw = vaw > 0.f ? vaw : NEG_SLOPE * vaw;
        float pA = vax * a4.x + vay * a4.y + vaz * a4.z + vaw * a4.w;
        pA += __shfl_xor(pA, 1);
        pA += __shfl_xor(pA, 2);
        pA += __shfl_xor(pA, 4);
        pA += __shfl_xor(pA, 8);
        float nmA = fmaxf(mA, pA);
        float scA = __expf(mA - nmA), peA = __expf(pA - nmA);
        sA = sA * scA + peA;
        accA.x = accA.x * scA + peA * xa.x;
        accA.y = accA.y * scA + peA * xa.y;
        accA.z = accA.z * scA + peA * xa.z;
        accA.w = accA.w * scA + peA * xa.w;
        mA = nmA;
    }
    // merge states (mB may be -inf when degree==1: cB -> 0)
    float m = fmaxf(mA, mB);
    float cA = __expf(mA - m), cB = __expf(mB - m);
    float s = sA * cA + sB * cB;
    float ax = accA.x * cA + accB.x * cB;
    float ay = accA.y * cA + accB.y * cB;
    float az = accA.z * cA + accB.z * cB;
    float aw = accA.w * cA + accB.w * cB;

    float inv = 1.f / (s + 1e-16f);
    float4 b4 = *reinterpret_cast<const float4*>(bias + c4);
    float ox = ax * inv + b4.x;
    float oy = ay * inv + b4.y;
    float oz = az * inv + b4.z;
    float ow = aw * inv + b4.w;

    float lsum = ox + oy + oz + ow;
    float lsq  = ox * ox + oy * oy + oz * oz + ow * ow;
#pragma unroll
    for (int off = 1; off < 64; off <<= 1) {
        lsum += __shfl_xor(lsum, off);
        lsq  += __shfl_xor(lsq, off);
    }
    float mu = lsum * (1.f / 256.f);
    float var = lsq * (1.f / 256.f) - mu * mu;
    float rstd = rsqrtf(var + LN_EPS);
    float4 g4  = *reinterpret_cast<const float4*>(ln_g + c4);
    float4 lb4 = *reinterpret_cast<const float4*>(ln_b + c4);
    float4 hv  = *reinterpret_cast<const float4*>(h + (size_t)node * DIM + c4);
    hv.x += (ox - mu) * rstd * g4.x + lb4.x;
    hv.y += (oy - mu) * rstd * g4.y + lb4.y;
    hv.z += (oz - mu) * rstd * g4.z + lb4.z;
    hv.w += (ow - mu) * rstd * g4.w + lb4.w;
    *reinterpret_cast<float4*>(h + (size_t)node * DIM + c4) = hv;
    *reinterpret_cast<ushort4*>(h_bf + (size_t)node * DIM + c4) =
        make_ushort4(f2bf(hv.x), f2bf(hv.y), f2bf(hv.z), f2bf(hv.w));
}

// ---------------- final L2 row-normalize ----------------
__global__ __launch_bounds__(256) void normalize_kernel(const float* __restrict__ h,
                                                        float* __restrict__ out) {
    const int wave = threadIdx.x >> 6;
    const int lane = threadIdx.x & 63;
    const int node = blockIdx.x * 4 + wave;
    if (node >= N_NODES) return;
    float4 v = *reinterpret_cast<const float4*>(h + (size_t)node * DIM + (lane << 2));
    float sq = v.x * v.x + v.y * v.y + v.z * v.z + v.w * v.w;
#pragma unroll
    for (int off = 1; off < 64; off <<= 1) sq += __shfl_xor(sq, off);
    float inv = 1.f / fmaxf(sqrtf(sq), 1e-12f);
    float4 o = make_float4(v.x * inv, v.y * inv, v.z * inv, v.w * inv);
    *reinterpret_cast<float4*>(out + (size_t)node * DIM + (lane << 2)) = o;
}

extern "C" void kernel_launch(void* const* d_in, const int* in_sizes, int n_in,
                              void* d_out, int out_size, void* d_ws, size_t ws_size,
                              hipStream_t stream) {
    const float* x    = (const float*)d_in[0];
    const int*   ei   = (const int*)d_in[1];
    const float* w_in = (const float*)d_in[2];
    const float* b_in = (const float*)d_in[3];
    const float* wl   = (const float*)d_in[4];
    const float* wr   = (const float*)d_in[5];
    const float* att  = (const float*)d_in[6];
    const float* bias = (const float*)d_in[7];
    const float* ln_g = (const float*)d_in[8];
    const float* ln_b = (const float*)d_in[9];

    char* p = (char*)d_ws;
    float* h      = (float*)p;            p += (size_t)N_NODES * DIM * 4;   // 20.48 MB
    u16*   h_bf   = (u16*)p;              p += (size_t)N_NODES * DIM * 2;   // 10.24 MB
    u16*   xlr_bf = (u16*)p;              p += (size_t)N_NODES * 512 * 2;   // 20.48 MB
    u16*   w_bf   = (u16*)p;              p += (size_t)W_TOT * 2;           // ~1 MB
    int* row_ptr  = (int*)p;              p += (N_NODES + 1) * 4;
    int* counts   = (int*)p;              p += N_NODES * 4;
    int* cursor   = (int*)p;              p += N_NODES * 4;
    int* csr_src  = (int*)p;

    // x_bf aliases xlr_bf (only needed for the input projection, before layer GEMMs)
    u16* x_bf = xlr_bf;

    hipMemsetAsync(counts, 0, sizeof(int) * 2 * N_NODES, stream);
    count_kernel<<<(E_TOT + 255) / 256, 256, 0, stream>>>(ei, counts);
    scan_kernel<<<1, 1024, 0, stream>>>(counts, row_ptr);
    scatter_kernel<<<(E_TOT + 255) / 256, 256, 0, stream>>>(ei, row_ptr, cursor, csr_src);

    {
        int n4 = N_NODES * IN_DIM / 4;
        convert_bf16<<<(n4 + 255) / 256, 256, 0, stream>>>(x, x_bf, n4);
        convert_weights<<<(W_TOT + 255) / 256, 256, 0, stream>>>(w_in, wl, wr, w_bf);
    }

    // input projection: h = x @ w_in + b_in (f32 + bf16 copies)
    gemm_mfma<IN_DIM, 0><<<dim3(DIM / BN, (N_NODES + BM - 1) / BM), 256, 0, stream>>>(
        x_bf, w_bf, b_in, h, h_bf, N_NODES, DIM);

    for (int l = 0; l < LAYERS; ++l) {
        const u16* wlr = w_bf + W_IN_ELEMS + (size_t)l * W_LR_ELEMS;  // [512][256]
        gemm_mfma<DIM, 1><<<dim3(512 / BN, (N_NODES + BM - 1) / BM), 256, 0, stream>>>(
            h_bf, wlr, nullptr, nullptr, xlr_bf, N_NODES, 512);
        gat_edge<<<(N_NODES + 3) / 4, 256, 0, stream>>>(
            xlr_bf, row_ptr, csr_src,
            att + (size_t)l * DIM, bias + (size_t)l * DIM,
            ln_g + (size_t)l * DIM, ln_b + (size_t)l * DIM, h, h_bf);
    }

    normalize_kernel<<<(N_NODES + 3) / 4, 256, 0, stream>>>(h, (float*)d_out);
}